// Round 7
// baseline (328.237 us; speedup 1.0000x reference)
//
#include <hip/hip_runtime.h>

// DigitCapsules dynamic routing. Round-24 = one-block-per-batch routing.
//  - R23: 135 us. ut (94 MB) written once, read TWICE; psum re-read ~22
//    scalar loads/block/iter; 6 launches (5 gaps).
//  - FIX: k_route = 256 blocks (1/CU), 576 threads (9 waves), 2 caps/thread.
//    Each thread holds u for its 2 capsules x 10 classes in 40 u4 regs
//    (160 VGPR). Both routing iterations + final squash run in-block with
//    __syncthreads only (dependency is per-batch). ut read ONCE. psum
//    buffers deleted (bfly16 + 9-wave LDS fold). k_uhat loses its s0 tail
//    (s0 = 0.1*Sum(u_f16) now; absmax headroom 4.4x).
//  - k_pack = pack_W + pack_x fused (one launch).
//  - Pipeline (3 launches): k_pack, k_uhat, k_route. Predicted ~100-110 us.

#define NCLS   10
#define NCAPS  1152
#define KDO    16
#define CHUNK  128
#define NCH    9           // 1152 / 128
#define NB     256
#define BBAT   8           // batches per k_uhat block
#define TR     576         // k_route threads: 9 waves, 2 capsules/thread

typedef _Float16 h2_t __attribute__((ext_vector_type(2)));
typedef unsigned u4 __attribute__((ext_vector_type(4)));

static __device__ __forceinline__ unsigned pack2h(float a, float b) {
    union { _Float16 h[2]; unsigned u; } p;
    p.h[0] = (_Float16)a;
    p.h[1] = (_Float16)b;
    return p.u;
}

static __device__ __forceinline__ float dot8h(u4 r, const unsigned* xh) {
    union { unsigned u; h2_t h; } w0, w1, w2, w3, a0, a1, a2, a3;
    w0.u = r.x; w1.u = r.y; w2.u = r.z; w3.u = r.w;
    a0.u = xh[0]; a1.u = xh[1]; a2.u = xh[2]; a3.u = xh[3];
#if __has_builtin(__builtin_amdgcn_fdot2)
    float acc = __builtin_amdgcn_fdot2(w0.h, a0.h, 0.f, false);
    acc = __builtin_amdgcn_fdot2(w1.h, a1.h, acc, false);
    acc = __builtin_amdgcn_fdot2(w2.h, a2.h, acc, false);
    acc = __builtin_amdgcn_fdot2(w3.h, a3.h, acc, false);
    return acc;
#else
    return (float)w0.h.x * (float)a0.h.x + (float)w0.h.y * (float)a0.h.y
         + (float)w1.h.x * (float)a1.h.x + (float)w1.h.y * (float)a1.h.y
         + (float)w2.h.x * (float)a2.h.x + (float)w2.h.y * (float)a2.h.y
         + (float)w3.h.x * (float)a3.h.x + (float)w3.h.y * (float)a3.h.y;
#endif
}

static __device__ __forceinline__ float dot2h(unsigned a, unsigned b, float acc) {
    union { unsigned u; h2_t h; } pa, pb;
    pa.u = a; pb.u = b;
#if __has_builtin(__builtin_amdgcn_fdot2)
    return __builtin_amdgcn_fdot2(pa.h, pb.h, acc, false);
#else
    return acc + (float)pa.h.x * (float)pb.h.x + (float)pa.h.y * (float)pb.h.y;
#endif
}

// Butterfly reduce of 16 per-lane values across a 64-lane wave: 17 shuffles.
// Lane l ends with S[d(l)], d = (l&4?1:0)|(l&8?2:0)|(l&16?4:0)|(l&32?8:0).
static __device__ __forceinline__ float bfly16(const float v[KDO], int lane) {
    float a[8];
    #pragma unroll
    for (int i = 0; i < 8; ++i) {
        float send = (lane & 32) ? v[i] : v[i + 8];
        float recv = __shfl_xor(send, 32, 64);
        float keep = (lane & 32) ? v[i + 8] : v[i];
        a[i] = keep + recv;
    }
    float b[4];
    #pragma unroll
    for (int i = 0; i < 4; ++i) {
        float send = (lane & 16) ? a[i] : a[i + 4];
        float recv = __shfl_xor(send, 16, 64);
        float keep = (lane & 16) ? a[i + 4] : a[i];
        b[i] = keep + recv;
    }
    float c[2];
    #pragma unroll
    for (int i = 0; i < 2; ++i) {
        float send = (lane & 8) ? b[i] : b[i + 2];
        float recv = __shfl_xor(send, 8, 64);
        float keep = (lane & 8) ? b[i + 2] : b[i];
        c[i] = keep + recv;
    }
    float e;
    {
        float send = (lane & 4) ? c[0] : c[1];
        float recv = __shfl_xor(send, 4, 64);
        float keep = (lane & 4) ? c[1] : c[0];
        e = keep + recv;
    }
    e += __shfl_xor(e, 2, 64);
    e += __shfl_xor(e, 1, 64);
    return e;
}

static __device__ __forceinline__ int bfly_d(int lane) {
    return ((lane & 4) ? 1 : 0) | ((lane & 8) ? 2 : 0)
         | ((lane & 16) ? 4 : 0) | ((lane & 32) ? 8 : 0);
}

// ---- fused input packing: blocks [0,720) pack W, [720,1872) pack x ----
// Wt[c][d][i] : u4 of 8 f16 W[c,i,0,d,:]; xp[b][i] : u4 of 8 f16 x[b,i,:]
__global__ __launch_bounds__(256)
void k_pack(const float4* __restrict__ W4, u4* __restrict__ Wt,
            const float4* __restrict__ x4, u4* __restrict__ xp) {
    int bid = blockIdx.x;
    if (bid < 720) {                      // 720*256 == NCLS*NCAPS*KDO exactly
        int tid = bid * 256 + threadIdx.x;          // (c*NCAPS+i)*KDO + d
        int d = tid & 15;
        int rest = tid >> 4;
        int i = rest % NCAPS;
        int c = rest / NCAPS;
        float4 a = W4[2 * tid];
        float4 b = W4[2 * tid + 1];
        u4 o;
        o.x = pack2h(a.x, a.y);
        o.y = pack2h(a.z, a.w);
        o.z = pack2h(b.x, b.y);
        o.w = pack2h(b.z, b.w);
        Wt[(size_t)(c * KDO + d) * NCAPS + i] = o;
    } else {                              // 1152*256 == NB*NCAPS exactly
        int tid = (bid - 720) * 256 + threadIdx.x;  // b*NCAPS + i
        float4 a = x4[2 * tid];
        float4 b = x4[2 * tid + 1];
        u4 o;
        o.x = pack2h(a.x, a.y);
        o.y = pack2h(a.z, a.w);
        o.z = pack2h(b.x, b.y);
        o.w = pack2h(b.z, b.w);
        xp[tid] = o;
    }
}

// ---- phase 1: ut only (no s0 tail). grid (NCH, NB/8, 5), 128 threads. ----
__global__ __launch_bounds__(CHUNK, 1)
void k_uhat(const u4* __restrict__ Wt, const u4* __restrict__ xp,
            u4* __restrict__ ut)
{
    const int t  = threadIdx.x;
    const int ii = blockIdx.x * CHUNK + t;
    const int b0 = blockIdx.y * BBAT;
    const int c0 = blockIdx.z * 2;

    u4 xq[BBAT];
    #pragma unroll
    for (int k = 0; k < BBAT; ++k)
        xq[k] = xp[(size_t)(b0 + k) * NCAPS + ii];

    #pragma unroll
    for (int cc = 0; cc < 2; ++cc) {
        const int c = c0 + cc;
        const u4* base = Wt + (size_t)c * KDO * NCAPS + ii;
        u4 r[KDO];                                 // 16 loads in flight
        #pragma unroll
        for (int d = 0; d < KDO; ++d)
            r[d] = base[(size_t)d * NCAPS];        // regular load: W stays L2

        #pragma unroll
        for (int k = 0; k < BBAT; ++k) {           // reuse W for 8 batches
            const unsigned* xh = (const unsigned*)&xq[k];
            u4 h0, h1;
            #pragma unroll
            for (int dp = 0; dp < 8; ++dp) {
                float u0 = dot8h(r[2 * dp],     xh);
                float u1 = dot8h(r[2 * dp + 1], xh);
                unsigned pk = pack2h(u0, u1);
                if (dp < 4) ((unsigned*)&h0)[dp] = pk;
                else        ((unsigned*)&h1)[dp - 4] = pk;
            }
            u4* utb = ut + (size_t)(b0 + k) * NCLS * 2 * NCAPS;
            utb[((size_t)c * 2 + 0) * NCAPS + ii] = h0;
            utb[((size_t)c * 2 + 1) * NCAPS + ii] = h1;
        }
    }
}

// ---- phase 2: full routing, one block per batch. 576 thr = 9 waves,
// 2 capsules/thread (i0 = t, i1 = t+576). u held in 40 u4 registers.
__global__ __launch_bounds__(TR, 1)
void k_route(const u4* __restrict__ ut, float* __restrict__ out)
{
    __shared__ float red[9][NCLS * KDO];           // per-wave partials, 5.76 KB
    __shared__ float v0sh[NCLS * KDO];             // v0 (f32)
    __shared__ unsigned vsh[NCLS * 8];             // packed v for logits
    const int t    = threadIdx.x;
    const int lane = t & 63;
    const int wave = t >> 6;
    const int b    = blockIdx.x;
    const int dm   = bfly_d(lane);
    const u4* utb  = ut + (size_t)b * NCLS * 2 * NCAPS;

    // load u for 2 capsules x 10 classes (coalesced; 40 x 16B per thread)
    u4 p00[NCLS], p01[NCLS], p10[NCLS], p11[NCLS];
    #pragma unroll
    for (int c = 0; c < NCLS; ++c) {
        p00[c] = utb[((size_t)c * 2 + 0) * NCAPS + t];
        p01[c] = utb[((size_t)c * 2 + 1) * NCAPS + t];
        p10[c] = utb[((size_t)c * 2 + 0) * NCAPS + t + TR];
        p11[c] = utb[((size_t)c * 2 + 1) * NCAPS + t + TR];
    }

    // ---------- round 0: s0 = 0.1 * sum_i u ; v0 = squash(s0) ----------
    #pragma unroll
    for (int c = 0; c < NCLS; ++c) {
        float sacc[KDO];
        #pragma unroll
        for (int dp = 0; dp < 8; ++dp) {
            union { unsigned u; h2_t h; } pa, pb;
            pa.u = (dp < 4) ? ((const unsigned*)&p00[c])[dp]
                            : ((const unsigned*)&p01[c])[dp - 4];
            pb.u = (dp < 4) ? ((const unsigned*)&p10[c])[dp]
                            : ((const unsigned*)&p11[c])[dp - 4];
            sacc[2 * dp]     = (float)pa.h.x + (float)pb.h.x;
            sacc[2 * dp + 1] = (float)pa.h.y + (float)pb.h.y;
        }
        float e = bfly16(sacc, lane);
        if ((lane & 3) == 0) red[wave][c * KDO + dm] = e;
    }
    __syncthreads();
    if (t < NCLS * KDO) {                          // fold 9 waves + squash
        float s = 0.f;
        #pragma unroll
        for (int w = 0; w < 9; ++w) s += red[w][t];
        s *= 0.1f;
        float nsq = s * s;
        nsq += __shfl_xor(nsq, 8, 16);
        nsq += __shfl_xor(nsq, 4, 16);
        nsq += __shfl_xor(nsq, 2, 16);
        nsq += __shfl_xor(nsq, 1, 16);
        float sc = sqrtf(nsq) / (1.f + nsq);
        float vv = s * sc;
        v0sh[t] = vv;
        float a  = __shfl(vv, (lane & 48) + 2 * (lane & 7), 64);
        float b2 = __shfl(vv, (lane & 48) + 2 * (lane & 7) + 1, 64);
        if ((lane & 15) < 8) vsh[(t >> 4) * 8 + (t & 7)] = pack2h(a, b2);
    }
    __syncthreads();

    // ---------- rounds 1..2: logits -> softmax -> weighted sum ----------
    #pragma unroll
    for (int it = 0; it < 2; ++it) {
        float bl0[NCLS], bl1[NCLS];
        #pragma unroll
        for (int c = 0; c < NCLS; ++c) {
            float a0 = 0.f, a1 = 0.f;
            #pragma unroll
            for (int dp = 0; dp < 4; ++dp) {
                unsigned vv0 = vsh[c * 8 + dp];
                a0 = dot2h(((const unsigned*)&p00[c])[dp], vv0, a0);
                a1 = dot2h(((const unsigned*)&p10[c])[dp], vv0, a1);
            }
            #pragma unroll
            for (int dp = 0; dp < 4; ++dp) {
                unsigned vv1 = vsh[c * 8 + 4 + dp];
                a0 = dot2h(((const unsigned*)&p01[c])[dp], vv1, a0);
                a1 = dot2h(((const unsigned*)&p11[c])[dp], vv1, a1);
            }
            bl0[c] = a0; bl1[c] = a1;
        }
        float m0 = bl0[0], m1 = bl1[0];
        #pragma unroll
        for (int c = 1; c < NCLS; ++c) { m0 = fmaxf(m0, bl0[c]); m1 = fmaxf(m1, bl1[c]); }
        float d0 = 0.f, d1 = 0.f;
        #pragma unroll
        for (int c = 0; c < NCLS; ++c) { d0 += __expf(bl0[c] - m0); d1 += __expf(bl1[c] - m1); }
        float s0i = 1.f / d0, s1i = 1.f / d1;
        #pragma unroll
        for (int c = 0; c < NCLS; ++c) {
            bl0[c] = __expf(bl0[c] - m0) * s0i;    // bl := w
            bl1[c] = __expf(bl1[c] - m1) * s1i;
        }

        #pragma unroll
        for (int c = 0; c < NCLS; ++c) {
            float sacc[KDO];
            #pragma unroll
            for (int dp = 0; dp < 8; ++dp) {
                union { unsigned u; h2_t h; } pa, pb;
                pa.u = (dp < 4) ? ((const unsigned*)&p00[c])[dp]
                                : ((const unsigned*)&p01[c])[dp - 4];
                pb.u = (dp < 4) ? ((const unsigned*)&p10[c])[dp]
                                : ((const unsigned*)&p11[c])[dp - 4];
                sacc[2 * dp]     = bl0[c] * (float)pa.h.x + bl1[c] * (float)pb.h.x;
                sacc[2 * dp + 1] = bl0[c] * (float)pa.h.y + bl1[c] * (float)pb.h.y;
            }
            float e = bfly16(sacc, lane);
            if ((lane & 3) == 0) red[wave][c * KDO + dm] = e;
        }
        __syncthreads();
        if (t < NCLS * KDO) {
            float s = 0.f;
            #pragma unroll
            for (int w = 0; w < 9; ++w) s += red[w][t];
            float nsq = s * s;
            nsq += __shfl_xor(nsq, 8, 16);
            nsq += __shfl_xor(nsq, 4, 16);
            nsq += __shfl_xor(nsq, 2, 16);
            nsq += __shfl_xor(nsq, 1, 16);
            float sc = sqrtf(nsq) / (1.f + nsq);
            float vv = s * sc;
            if (it == 0) {                         // pack v0+v1 for logits2
                float vt = vv + v0sh[t];
                float a  = __shfl(vt, (lane & 48) + 2 * (lane & 7), 64);
                float b2 = __shfl(vt, (lane & 48) + 2 * (lane & 7) + 1, 64);
                if ((lane & 15) < 8) vsh[(t >> 4) * 8 + (t & 7)] = pack2h(a, b2);
            } else {
                out[(size_t)b * NCLS * KDO + t] = vv;
            }
        }
        __syncthreads();
    }
}

// ---- fallback (small ws): round-1 fp32 fused kernel, proven correct ----
__global__ __launch_bounds__(256, 2)
void caps_routing_fb(const float* __restrict__ x, const float* __restrict__ W,
                     float* __restrict__ out)
{
    const int b    = blockIdx.x;
    const int t    = threadIdx.x;
    const int lane = t & 63;
    const int wave = t >> 6;
    __shared__ float v_prev[NCLS * KDO];
    __shared__ float redf[NCLS * 4 * KDO];
    float4 xr[5][2];
    const float4* x4 = reinterpret_cast<const float4*>(x + (size_t)b * NCAPS * 8);
    #pragma unroll
    for (int j = 0; j < 5; ++j) {
        int i = t + 256 * j;
        if (i < NCAPS) { xr[j][0] = x4[2 * i]; xr[j][1] = x4[2 * i + 1]; }
    }
    float blog[5][NCLS];
    #pragma unroll
    for (int j = 0; j < 5; ++j)
        #pragma unroll
        for (int c = 0; c < NCLS; ++c) blog[j][c] = 0.f;
    const float4* W4 = reinterpret_cast<const float4*>(W);
    for (int it = 0; it < 3; ++it) {
        if (it > 0) {
            for (int c = 0; c < NCLS; ++c) {
                float vp[KDO];
                #pragma unroll
                for (int d = 0; d < KDO; ++d) vp[d] = v_prev[c * KDO + d];
                #pragma unroll
                for (int j = 0; j < 5; ++j) {
                    int i = t + 256 * j;
                    if (i < NCAPS) {
                        size_t wbx = (size_t)(c * NCAPS + i) * 32;
                        float a = 0.f;
                        #pragma unroll
                        for (int d = 0; d < KDO; ++d) {
                            float4 w0 = W4[wbx + 2 * d]; float4 w1 = W4[wbx + 2 * d + 1];
                            float u = w0.x*xr[j][0].x + w0.y*xr[j][0].y + w0.z*xr[j][0].z
                                    + w0.w*xr[j][0].w + w1.x*xr[j][1].x + w1.y*xr[j][1].y
                                    + w1.z*xr[j][1].z + w1.w*xr[j][1].w;
                            a += u * vp[d];
                        }
                        blog[j][c] += a;
                    }
                }
            }
        }
        float sm2[5], sid2[5];
        #pragma unroll
        for (int j = 0; j < 5; ++j) {
            int i = t + 256 * j;
            if (i < NCAPS) {
                float m = blog[j][0];
                #pragma unroll
                for (int c = 1; c < NCLS; ++c) m = fmaxf(m, blog[j][c]);
                float den = 0.f;
                #pragma unroll
                for (int c = 0; c < NCLS; ++c) den += __expf(blog[j][c] - m);
                sm2[j] = m; sid2[j] = 1.f / den;
            }
        }
        for (int c = 0; c < NCLS; ++c) {
            float acc[KDO];
            #pragma unroll
            for (int d = 0; d < KDO; ++d) acc[d] = 0.f;
            #pragma unroll
            for (int j = 0; j < 5; ++j) {
                int i = t + 256 * j;
                if (i < NCAPS) {
                    float wq = __expf(blog[j][c] - sm2[j]) * sid2[j];
                    size_t wbx = (size_t)(c * NCAPS + i) * 32;
                    #pragma unroll
                    for (int d = 0; d < KDO; ++d) {
                        float4 w0 = W4[wbx + 2 * d]; float4 w1 = W4[wbx + 2 * d + 1];
                        float u = w0.x*xr[j][0].x + w0.y*xr[j][0].y + w0.z*xr[j][0].z
                                + w0.w*xr[j][0].w + w1.x*xr[j][1].x + w1.y*xr[j][1].y
                                + w1.z*xr[j][1].z + w1.w*xr[j][1].w;
                        acc[d] += wq * u;
                    }
                }
            }
            #pragma unroll
            for (int d = 0; d < KDO; ++d) {
                float v = acc[d];
                v += __shfl_xor(v, 32, 64); v += __shfl_xor(v, 16, 64);
                v += __shfl_xor(v,  8, 64); v += __shfl_xor(v,  4, 64);
                v += __shfl_xor(v,  2, 64); v += __shfl_xor(v,  1, 64);
                if (lane == 0) redf[(c * 4 + wave) * KDO + d] = v;
            }
        }
        __syncthreads();
        if (t < NCLS * KDO) {
            int c = t >> 4, d = t & 15;
            float s = redf[(c*4+0)*KDO+d] + redf[(c*4+1)*KDO+d]
                    + redf[(c*4+2)*KDO+d] + redf[(c*4+3)*KDO+d];
            float nsq = s * s;
            nsq += __shfl_xor(nsq, 8, 16); nsq += __shfl_xor(nsq, 4, 16);
            nsq += __shfl_xor(nsq, 2, 16); nsq += __shfl_xor(nsq, 1, 16);
            float scale = sqrtf(nsq) / (1.f + nsq);
            float vv = s * scale;
            v_prev[t] = vv;
            if (it == 2) out[(size_t)b * NCLS * KDO + t] = vv;
        }
        __syncthreads();
    }
}

extern "C" void kernel_launch(void* const* d_in, const int* in_sizes, int n_in,
                              void* d_out, int out_size, void* d_ws, size_t ws_size,
                              hipStream_t stream) {
    const float* x = (const float*)d_in[0];              // [256, 1152, 8] fp32
    const float4* W4 = (const float4*)d_in[1];           // [10, 1152, 1, 16, 8] fp32
    float* out = (float*)d_out;                          // [256, 10, 1, 16] fp32
    (void)in_sizes; (void)n_in; (void)out_size;

    const size_t WT = (size_t)NCLS * KDO * NCAPS * sizeof(u4);            //  2.95 MB
    const size_t XH = (size_t)NB * NCAPS * sizeof(u4);                    //  4.72 MB
    const size_t UT = (size_t)NB * NCLS * 2 * NCAPS * sizeof(u4);         // 94.37 MB
    const size_t need = WT + XH + UT;                                     // ~102 MB

    if (ws_size >= need) {
        char* p = (char*)d_ws;
        u4* Wt = (u4*)p; p += WT;
        u4* xp = (u4*)p; p += XH;
        u4* ut = (u4*)p;

        k_pack<<<dim3(720 + 1152), dim3(256), 0, stream>>>(
            W4, Wt, (const float4*)x, xp);
        k_uhat<<<dim3(NCH, NB / BBAT, NCLS / 2), dim3(CHUNK), 0, stream>>>(
            Wt, xp, ut);
        k_route<<<dim3(NB), dim3(TR), 0, stream>>>(ut, out);
    } else {
        caps_routing_fb<<<dim3(NB), dim3(256), 0, stream>>>(x, (const float*)d_in[1], out);
    }
}

// Round 8
// 134.277 us; speedup vs baseline: 2.4445x; 2.4445x over previous
//
#include <hip/hip_runtime.h>

// DigitCapsules dynamic routing. Round-25 = revert R24 (register-spill
// disaster: k_route VGPR 84 + 310 MB scratch traffic = 245 us) back to the
// proven R23 structure (135 us), plus one targeted fix:
//  - R23 k_uhat was GRID-limited: 1440 blocks x 2 waves = 2.8 waves/SIMD,
//    26% occupancy, 2.6 TB/s effective while writing 93.6 MB (latency-bound).
//  - FIX: 1 class per block (grid.z 5->10). Same mem-instrs per u-value
//    (8 xq + 16 W + 16 st per 128 outputs), but 5760 waves = 5.6/SIMD.
//    s0-tail becomes red0[2][8][16], exactly 128 psum entries = 1/thread.
//  - k_iter / k_squash / fused k_pack unchanged from the 135-us run.
//  - Pipeline (5 launches): k_pack, k_uhat(+s0), k_iter, k_iter, k_squash.
//    Predicted ~110-118 us.

#define NCLS   10
#define NCAPS  1152
#define KDO    16
#define CHUNK  128
#define NCH    9           // 1152 / 128
#define NB     256
#define BBAT   8           // batches per k_uhat block

typedef _Float16 h2_t __attribute__((ext_vector_type(2)));
typedef unsigned u4 __attribute__((ext_vector_type(4)));

static __device__ __forceinline__ unsigned pack2h(float a, float b) {
    union { _Float16 h[2]; unsigned u; } p;
    p.h[0] = (_Float16)a;
    p.h[1] = (_Float16)b;
    return p.u;
}

static __device__ __forceinline__ float dot8h(u4 r, const unsigned* xh) {
    union { unsigned u; h2_t h; } w0, w1, w2, w3, a0, a1, a2, a3;
    w0.u = r.x; w1.u = r.y; w2.u = r.z; w3.u = r.w;
    a0.u = xh[0]; a1.u = xh[1]; a2.u = xh[2]; a3.u = xh[3];
#if __has_builtin(__builtin_amdgcn_fdot2)
    float acc = __builtin_amdgcn_fdot2(w0.h, a0.h, 0.f, false);
    acc = __builtin_amdgcn_fdot2(w1.h, a1.h, acc, false);
    acc = __builtin_amdgcn_fdot2(w2.h, a2.h, acc, false);
    acc = __builtin_amdgcn_fdot2(w3.h, a3.h, acc, false);
    return acc;
#else
    return (float)w0.h.x * (float)a0.h.x + (float)w0.h.y * (float)a0.h.y
         + (float)w1.h.x * (float)a1.h.x + (float)w1.h.y * (float)a1.h.y
         + (float)w2.h.x * (float)a2.h.x + (float)w2.h.y * (float)a2.h.y
         + (float)w3.h.x * (float)a3.h.x + (float)w3.h.y * (float)a3.h.y;
#endif
}

static __device__ __forceinline__ float dot2h(unsigned a, unsigned b, float acc) {
    union { unsigned u; h2_t h; } pa, pb;
    pa.u = a; pb.u = b;
#if __has_builtin(__builtin_amdgcn_fdot2)
    return __builtin_amdgcn_fdot2(pa.h, pb.h, acc, false);
#else
    return acc + (float)pa.h.x * (float)pb.h.x + (float)pa.h.y * (float)pb.h.y;
#endif
}

// Butterfly reduce of 16 per-lane values across a 64-lane wave: 17 shuffles.
// Lane l ends with S[d(l)], d = (l&4?1:0)|(l&8?2:0)|(l&16?4:0)|(l&32?8:0).
static __device__ __forceinline__ float bfly16(const float v[KDO], int lane) {
    float a[8];
    #pragma unroll
    for (int i = 0; i < 8; ++i) {
        float send = (lane & 32) ? v[i] : v[i + 8];
        float recv = __shfl_xor(send, 32, 64);
        float keep = (lane & 32) ? v[i + 8] : v[i];
        a[i] = keep + recv;
    }
    float b[4];
    #pragma unroll
    for (int i = 0; i < 4; ++i) {
        float send = (lane & 16) ? a[i] : a[i + 4];
        float recv = __shfl_xor(send, 16, 64);
        float keep = (lane & 16) ? a[i + 4] : a[i];
        b[i] = keep + recv;
    }
    float c[2];
    #pragma unroll
    for (int i = 0; i < 2; ++i) {
        float send = (lane & 8) ? b[i] : b[i + 2];
        float recv = __shfl_xor(send, 8, 64);
        float keep = (lane & 8) ? b[i + 2] : b[i];
        c[i] = keep + recv;
    }
    float e;
    {
        float send = (lane & 4) ? c[0] : c[1];
        float recv = __shfl_xor(send, 4, 64);
        float keep = (lane & 4) ? c[1] : c[0];
        e = keep + recv;
    }
    e += __shfl_xor(e, 2, 64);
    e += __shfl_xor(e, 1, 64);
    return e;
}

static __device__ __forceinline__ int bfly_d(int lane) {
    return ((lane & 4) ? 1 : 0) | ((lane & 8) ? 2 : 0)
         | ((lane & 16) ? 4 : 0) | ((lane & 32) ? 8 : 0);
}

// ---- fused input packing: blocks [0,720) pack W, [720,1872) pack x ----
// Wt[c][d][i] : u4 of 8 f16 W[c,i,0,d,:]; xp[b][i] : u4 of 8 f16 x[b,i,:]
__global__ __launch_bounds__(256)
void k_pack(const float4* __restrict__ W4, u4* __restrict__ Wt,
            const float4* __restrict__ x4, u4* __restrict__ xp) {
    int bid = blockIdx.x;
    if (bid < 720) {                      // 720*256 == NCLS*NCAPS*KDO exactly
        int tid = bid * 256 + threadIdx.x;          // (c*NCAPS+i)*KDO + d
        int d = tid & 15;
        int rest = tid >> 4;
        int i = rest % NCAPS;
        int c = rest / NCAPS;
        float4 a = W4[2 * tid];
        float4 b = W4[2 * tid + 1];
        u4 o;
        o.x = pack2h(a.x, a.y);
        o.y = pack2h(a.z, a.w);
        o.z = pack2h(b.x, b.y);
        o.w = pack2h(b.z, b.w);
        Wt[(size_t)(c * KDO + d) * NCAPS + i] = o;
    } else {                              // 1152*256 == NB*NCAPS exactly
        int tid = (bid - 720) * 256 + threadIdx.x;  // b*NCAPS + i
        float4 a = x4[2 * tid];
        float4 b = x4[2 * tid + 1];
        u4 o;
        o.x = pack2h(a.x, a.y);
        o.y = pack2h(a.z, a.w);
        o.z = pack2h(b.x, b.y);
        o.w = pack2h(b.z, b.w);
        xp[tid] = o;
    }
}

// ---- phase 1: ut + uniform-weight partial sums (s0).
// grid (NCH, NB/8, 10): 1 class x 8 batches per block, 128 threads = 2 waves.
// psum layout: [b][ch][c][d] f32 (9 chunk-partials per (b,c,d)).
__global__ __launch_bounds__(CHUNK, 1)
void k_uhat(const u4* __restrict__ Wt, const u4* __restrict__ xp,
            u4* __restrict__ ut, float* __restrict__ psum)
{
    __shared__ float red0[2][BBAT][KDO];           // [wave][k][d], 1 KB
    const int t    = threadIdx.x;
    const int lane = t & 63;
    const int wave = t >> 6;
    const int ii = blockIdx.x * CHUNK + t;
    const int b0 = blockIdx.y * BBAT;
    const int c  = blockIdx.z;
    const int dm = bfly_d(lane);

    u4 xq[BBAT];
    #pragma unroll
    for (int k = 0; k < BBAT; ++k)
        xq[k] = xp[(size_t)(b0 + k) * NCAPS + ii];

    const u4* base = Wt + (size_t)c * KDO * NCAPS + ii;
    u4 r[KDO];                                     // 16 loads in flight
    #pragma unroll
    for (int d = 0; d < KDO; ++d)
        r[d] = base[(size_t)d * NCAPS];            // regular load: W stays L2

    #pragma unroll
    for (int k = 0; k < BBAT; ++k) {               // reuse W for 8 batches
        const unsigned* xh = (const unsigned*)&xq[k];
        u4 h0, h1;
        float sacc[KDO];                           // f32 u before f16 rounding
        #pragma unroll
        for (int dp = 0; dp < 8; ++dp) {
            float u0 = dot8h(r[2 * dp],     xh);
            float u1 = dot8h(r[2 * dp + 1], xh);
            sacc[2 * dp]     = u0;
            sacc[2 * dp + 1] = u1;
            unsigned pk = pack2h(u0, u1);
            if (dp < 4) ((unsigned*)&h0)[dp] = pk;
            else        ((unsigned*)&h1)[dp - 4] = pk;
        }
        u4* utb = ut + (size_t)(b0 + k) * NCLS * 2 * NCAPS;
        utb[((size_t)c * 2 + 0) * NCAPS + ii] = h0;
        utb[((size_t)c * 2 + 1) * NCAPS + ii] = h1;

        // butterfly: 17 shuffles for all 16 d-sums
        float e = bfly16(sacc, lane);
        if ((lane & 3) == 0) red0[wave][k][dm] = e;
    }
    __syncthreads();
    {   // 8k x 16d = 128 entries, exactly one per thread
        int k = t >> 4, d = t & 15;
        float v = red0[0][k][d] + red0[1][k][d];
        psum[(((size_t)(b0 + k) * NCH + blockIdx.x) * NCLS + c) * KDO + d] = v;
    }
}

// ---- phase 2 (fused, x2): in-block v from psum + agreement + softmax +
// weighted partial-sum. grid (NCH, NB), 128 threads; reads ut ONCE.
// v_logit = squash(scaleA*sum(psA)) [+ squash(sum(psB)) if psB].
__global__ __launch_bounds__(CHUNK, 1)
void k_iter(const u4* __restrict__ ut,
            const float* __restrict__ psA, float scaleA,
            const float* __restrict__ psB,
            float* __restrict__ psOut)
{
    __shared__ float s0sh[NCLS * KDO];
    __shared__ float s1sh[NCLS * KDO];
    __shared__ float scsh[2][NCLS];
    __shared__ unsigned vsh[NCLS * 8];
    __shared__ float red[2][NCLS * KDO];               // per-wave partials
    const int t    = threadIdx.x;
    const int lane = t & 63;
    const int wave = t >> 6;
    const int ii = blockIdx.x * CHUNK + t;
    const int b  = blockIdx.y;
    const int dm = bfly_d(lane);

    // ---- in-block squash: s = sum of 9 chunk partials ----
    for (int tt = t; tt < NCLS * KDO; tt += CHUNK) {
        float s = 0.f;
        #pragma unroll
        for (int ch = 0; ch < NCH; ++ch)
            s += psA[((size_t)b * NCH + ch) * (NCLS * KDO) + tt];
        s0sh[tt] = s * scaleA;
        if (psB) {
            float s2 = 0.f;
            #pragma unroll
            for (int ch = 0; ch < NCH; ++ch)
                s2 += psB[((size_t)b * NCH + ch) * (NCLS * KDO) + tt];
            s1sh[tt] = s2;
        }
    }
    __syncthreads();
    if (t < (psB ? 2 * NCLS : NCLS)) {
        int which = t >= NCLS;
        int c = which ? t - NCLS : t;
        const float* ss = which ? s1sh : s0sh;
        float nsq = 0.f;
        #pragma unroll
        for (int d = 0; d < KDO; ++d) {
            float x = ss[c * KDO + d];
            nsq += x * x;
        }
        scsh[which][c] = sqrtf(nsq) / (1.f + nsq);
    }
    __syncthreads();
    if (t < NCLS * 8) {
        int c = t >> 3, dp = t & 7;
        float va = s0sh[c * KDO + 2 * dp]     * scsh[0][c];
        float vb = s0sh[c * KDO + 2 * dp + 1] * scsh[0][c];
        if (psB) {
            va += s1sh[c * KDO + 2 * dp]     * scsh[1][c];
            vb += s1sh[c * KDO + 2 * dp + 1] * scsh[1][c];
        }
        vsh[t] = pack2h(va, vb);
    }
    __syncthreads();

    // ---- agreement + softmax + weighted sum ----
    const u4* utb = ut + (size_t)b * NCLS * 2 * NCAPS;

    u4 up0[NCLS], up1[NCLS];
    #pragma unroll
    for (int c = 0; c < NCLS; ++c) {
        up0[c] = utb[((size_t)c * 2 + 0) * NCAPS + ii];
        up1[c] = utb[((size_t)c * 2 + 1) * NCAPS + ii];
    }

    float bl[NCLS];
    #pragma unroll
    for (int c = 0; c < NCLS; ++c) {
        float a = 0.f;
        #pragma unroll
        for (int dp = 0; dp < 4; ++dp)
            a = dot2h(((const unsigned*)&up0[c])[dp], vsh[c * 8 + dp], a);
        #pragma unroll
        for (int dp = 0; dp < 4; ++dp)
            a = dot2h(((const unsigned*)&up1[c])[dp], vsh[c * 8 + 4 + dp], a);
        bl[c] = a;
    }

    float m = bl[0];
    #pragma unroll
    for (int c = 1; c < NCLS; ++c) m = fmaxf(m, bl[c]);
    float den = 0.f;
    #pragma unroll
    for (int c = 0; c < NCLS; ++c) den += __expf(bl[c] - m);
    float sid = 1.f / den;
    #pragma unroll
    for (int c = 0; c < NCLS; ++c) bl[c] = __expf(bl[c] - m) * sid;  // bl := w

    #pragma unroll
    for (int c = 0; c < NCLS; ++c) {
        float sacc[KDO];
        #pragma unroll
        for (int dp = 0; dp < 8; ++dp) {
            union { unsigned u; h2_t h; } p;
            p.u = (dp < 4) ? ((const unsigned*)&up0[c])[dp]
                           : ((const unsigned*)&up1[c])[dp - 4];
            sacc[2 * dp]     = bl[c] * (float)p.h.x;
            sacc[2 * dp + 1] = bl[c] * (float)p.h.y;
        }
        float e = bfly16(sacc, lane);
        if ((lane & 3) == 0) red[wave][c * KDO + dm] = e;
    }
    __syncthreads();
    for (int tt = t; tt < NCLS * KDO; tt += CHUNK)
        psOut[((size_t)b * NCH + blockIdx.x) * (NCLS * KDO) + tt]
            = red[0][tt] + red[1][tt];
}

// ---- phase 3 (final only): sum 9 chunk-partials, squash, write out.
__global__ __launch_bounds__(160)
void k_squash(const float* __restrict__ psum, float* __restrict__ out)
{
    const int b = blockIdx.x;
    const int t = threadIdx.x;                         // 0..159
    if (t >= NCLS * KDO) return;

    float s = 0.f;
    #pragma unroll
    for (int ch = 0; ch < NCH; ++ch)
        s += psum[((size_t)b * NCH + ch) * (NCLS * KDO) + t];

    float nsq = s * s;                                 // reduce within c-group
    nsq += __shfl_xor(nsq, 8, 16);
    nsq += __shfl_xor(nsq, 4, 16);
    nsq += __shfl_xor(nsq, 2, 16);
    nsq += __shfl_xor(nsq, 1, 16);
    float sc = sqrtf(nsq) / (1.f + nsq);               // (nsq/(1+nsq))/sqrt(nsq)
    out[(size_t)b * NCLS * KDO + t] = s * sc;
}

// ---- fallback (small ws): round-1 fp32 fused kernel, proven correct ----
__global__ __launch_bounds__(256, 2)
void caps_routing_fb(const float* __restrict__ x, const float* __restrict__ W,
                     float* __restrict__ out)
{
    const int b    = blockIdx.x;
    const int t    = threadIdx.x;
    const int lane = t & 63;
    const int wave = t >> 6;
    __shared__ float v_prev[NCLS * KDO];
    __shared__ float redf[NCLS * 4 * KDO];
    float4 xr[5][2];
    const float4* x4 = reinterpret_cast<const float4*>(x + (size_t)b * NCAPS * 8);
    #pragma unroll
    for (int j = 0; j < 5; ++j) {
        int i = t + 256 * j;
        if (i < NCAPS) { xr[j][0] = x4[2 * i]; xr[j][1] = x4[2 * i + 1]; }
    }
    float blog[5][NCLS];
    #pragma unroll
    for (int j = 0; j < 5; ++j)
        #pragma unroll
        for (int c = 0; c < NCLS; ++c) blog[j][c] = 0.f;
    const float4* W4 = reinterpret_cast<const float4*>(W);
    for (int it = 0; it < 3; ++it) {
        if (it > 0) {
            for (int c = 0; c < NCLS; ++c) {
                float vp[KDO];
                #pragma unroll
                for (int d = 0; d < KDO; ++d) vp[d] = v_prev[c * KDO + d];
                #pragma unroll
                for (int j = 0; j < 5; ++j) {
                    int i = t + 256 * j;
                    if (i < NCAPS) {
                        size_t wbx = (size_t)(c * NCAPS + i) * 32;
                        float a = 0.f;
                        #pragma unroll
                        for (int d = 0; d < KDO; ++d) {
                            float4 w0 = W4[wbx + 2 * d]; float4 w1 = W4[wbx + 2 * d + 1];
                            float u = w0.x*xr[j][0].x + w0.y*xr[j][0].y + w0.z*xr[j][0].z
                                    + w0.w*xr[j][0].w + w1.x*xr[j][1].x + w1.y*xr[j][1].y
                                    + w1.z*xr[j][1].z + w1.w*xr[j][1].w;
                            a += u * vp[d];
                        }
                        blog[j][c] += a;
                    }
                }
            }
        }
        float sm2[5], sid2[5];
        #pragma unroll
        for (int j = 0; j < 5; ++j) {
            int i = t + 256 * j;
            if (i < NCAPS) {
                float m = blog[j][0];
                #pragma unroll
                for (int c = 1; c < NCLS; ++c) m = fmaxf(m, blog[j][c]);
                float den = 0.f;
                #pragma unroll
                for (int c = 0; c < NCLS; ++c) den += __expf(blog[j][c] - m);
                sm2[j] = m; sid2[j] = 1.f / den;
            }
        }
        for (int c = 0; c < NCLS; ++c) {
            float acc[KDO];
            #pragma unroll
            for (int d = 0; d < KDO; ++d) acc[d] = 0.f;
            #pragma unroll
            for (int j = 0; j < 5; ++j) {
                int i = t + 256 * j;
                if (i < NCAPS) {
                    float wq = __expf(blog[j][c] - sm2[j]) * sid2[j];
                    size_t wbx = (size_t)(c * NCAPS + i) * 32;
                    #pragma unroll
                    for (int d = 0; d < KDO; ++d) {
                        float4 w0 = W4[wbx + 2 * d]; float4 w1 = W4[wbx + 2 * d + 1];
                        float u = w0.x*xr[j][0].x + w0.y*xr[j][0].y + w0.z*xr[j][0].z
                                + w0.w*xr[j][0].w + w1.x*xr[j][1].x + w1.y*xr[j][1].y
                                + w1.z*xr[j][1].z + w1.w*xr[j][1].w;
                        acc[d] += wq * u;
                    }
                }
            }
            #pragma unroll
            for (int d = 0; d < KDO; ++d) {
                float v = acc[d];
                v += __shfl_xor(v, 32, 64); v += __shfl_xor(v, 16, 64);
                v += __shfl_xor(v,  8, 64); v += __shfl_xor(v,  4, 64);
                v += __shfl_xor(v,  2, 64); v += __shfl_xor(v,  1, 64);
                if (lane == 0) redf[(c * 4 + wave) * KDO + d] = v;
            }
        }
        __syncthreads();
        if (t < NCLS * KDO) {
            int c = t >> 4, d = t & 15;
            float s = redf[(c*4+0)*KDO+d] + redf[(c*4+1)*KDO+d]
                    + redf[(c*4+2)*KDO+d] + redf[(c*4+3)*KDO+d];
            float nsq = s * s;
            nsq += __shfl_xor(nsq, 8, 16); nsq += __shfl_xor(nsq, 4, 16);
            nsq += __shfl_xor(nsq, 2, 16); nsq += __shfl_xor(nsq, 1, 16);
            float scale = sqrtf(nsq) / (1.f + nsq);
            float vv = s * scale;
            v_prev[t] = vv;
            if (it == 2) out[(size_t)b * NCLS * KDO + t] = vv;
        }
        __syncthreads();
    }
}

extern "C" void kernel_launch(void* const* d_in, const int* in_sizes, int n_in,
                              void* d_out, int out_size, void* d_ws, size_t ws_size,
                              hipStream_t stream) {
    const float* x = (const float*)d_in[0];              // [256, 1152, 8] fp32
    const float4* W4 = (const float4*)d_in[1];           // [10, 1152, 1, 16, 8] fp32
    float* out = (float*)d_out;                          // [256, 10, 1, 16] fp32
    (void)in_sizes; (void)n_in; (void)out_size;

    const size_t WT = (size_t)NCLS * KDO * NCAPS * sizeof(u4);            //  2.95 MB
    const size_t XH = (size_t)NB * NCAPS * sizeof(u4);                    //  4.72 MB
    const size_t UT = (size_t)NB * NCLS * 2 * NCAPS * sizeof(u4);         // 94.37 MB
    const size_t PS = (size_t)NB * NCH * NCLS * KDO * sizeof(float);      //  1.47 MB
    const size_t need = WT + XH + UT + 3 * PS;                            // ~106 MB

    if (ws_size >= need) {
        char* p = (char*)d_ws;
        u4* Wt    = (u4*)p;    p += WT;
        u4* xp    = (u4*)p;    p += XH;
        u4* ut    = (u4*)p;    p += UT;
        float* ps0 = (float*)p; p += PS;
        float* ps1 = (float*)p; p += PS;
        float* ps2 = (float*)p;

        k_pack<<<dim3(720 + 1152), dim3(256), 0, stream>>>(
            W4, Wt, (const float4*)x, xp);
        k_uhat<<<dim3(NCH, NB / BBAT, NCLS), dim3(CHUNK), 0, stream>>>(
            Wt, xp, ut, ps0);
        k_iter<<<dim3(NCH, NB), dim3(CHUNK), 0, stream>>>(ut, ps0, 0.1f, nullptr, ps1);
        k_iter<<<dim3(NCH, NB), dim3(CHUNK), 0, stream>>>(ut, ps0, 0.1f, ps1, ps2);
        k_squash<<<dim3(NB), dim3(160), 0, stream>>>(ps2, out);
    } else {
        caps_routing_fb<<<dim3(NB), dim3(256), 0, stream>>>(x, (const float*)d_in[1], out);
    }
}

// Round 10
// 133.456 us; speedup vs baseline: 2.4595x; 1.0062x over previous
//
#include <hip/hip_runtime.h>

// DigitCapsules dynamic routing. Round-27 = R25 (proven 134 us, plain
// launches only) + vectorized psum traffic.
//  - R26 LESSON: hipLaunchCooperativeKernel inside the harness's graph
//    capture crashes the driver (ExceptionGroup). No cooperative launches.
//  - k_iter is instr-bound (~73cyc/wave-mem-instr, VALUBusy 18%). Its psum
//    re-derivation was 18-36 SCALAR loads/thread + 2 strided scalar stores.
//    FIX: float4 psum sums (40x16B per ch-slice; wave0=psA, wave1=psB run
//    in parallel), float4 psOut write (40 threads). Same bytes, same op
//    order -> bitwise-identical output. k_squash same treatment.
//  - Everything else byte-identical to R25.
//  - Pipeline (5 launches): k_pack, k_uhat(+s0), k_iter, k_iter, k_squash.
//    Predicted 134 -> ~122-127 us.

#define NCLS   10
#define NCAPS  1152
#define KDO    16
#define CHUNK  128
#define NCH    9           // 1152 / 128
#define NB     256
#define BBAT   8           // batches per k_uhat block

typedef _Float16 h2_t __attribute__((ext_vector_type(2)));
typedef unsigned u4 __attribute__((ext_vector_type(4)));

static __device__ __forceinline__ unsigned pack2h(float a, float b) {
    union { _Float16 h[2]; unsigned u; } p;
    p.h[0] = (_Float16)a;
    p.h[1] = (_Float16)b;
    return p.u;
}

static __device__ __forceinline__ float dot8h(u4 r, const unsigned* xh) {
    union { unsigned u; h2_t h; } w0, w1, w2, w3, a0, a1, a2, a3;
    w0.u = r.x; w1.u = r.y; w2.u = r.z; w3.u = r.w;
    a0.u = xh[0]; a1.u = xh[1]; a2.u = xh[2]; a3.u = xh[3];
#if __has_builtin(__builtin_amdgcn_fdot2)
    float acc = __builtin_amdgcn_fdot2(w0.h, a0.h, 0.f, false);
    acc = __builtin_amdgcn_fdot2(w1.h, a1.h, acc, false);
    acc = __builtin_amdgcn_fdot2(w2.h, a2.h, acc, false);
    acc = __builtin_amdgcn_fdot2(w3.h, a3.h, acc, false);
    return acc;
#else
    return (float)w0.h.x * (float)a0.h.x + (float)w0.h.y * (float)a0.h.y
         + (float)w1.h.x * (float)a1.h.x + (float)w1.h.y * (float)a1.h.y
         + (float)w2.h.x * (float)a2.h.x + (float)w2.h.y * (float)a2.h.y
         + (float)w3.h.x * (float)a3.h.x + (float)w3.h.y * (float)a3.h.y;
#endif
}

static __device__ __forceinline__ float dot2h(unsigned a, unsigned b, float acc) {
    union { unsigned u; h2_t h; } pa, pb;
    pa.u = a; pb.u = b;
#if __has_builtin(__builtin_amdgcn_fdot2)
    return __builtin_amdgcn_fdot2(pa.h, pb.h, acc, false);
#else
    return acc + (float)pa.h.x * (float)pb.h.x + (float)pa.h.y * (float)pb.h.y;
#endif
}

// Butterfly reduce of 16 per-lane values across a 64-lane wave: 17 shuffles.
// Lane l ends with S[d(l)], d = (l&4?1:0)|(l&8?2:0)|(l&16?4:0)|(l&32?8:0).
static __device__ __forceinline__ float bfly16(const float v[KDO], int lane) {
    float a[8];
    #pragma unroll
    for (int i = 0; i < 8; ++i) {
        float send = (lane & 32) ? v[i] : v[i + 8];
        float recv = __shfl_xor(send, 32, 64);
        float keep = (lane & 32) ? v[i + 8] : v[i];
        a[i] = keep + recv;
    }
    float b[4];
    #pragma unroll
    for (int i = 0; i < 4; ++i) {
        float send = (lane & 16) ? a[i] : a[i + 4];
        float recv = __shfl_xor(send, 16, 64);
        float keep = (lane & 16) ? a[i + 4] : a[i];
        b[i] = keep + recv;
    }
    float c[2];
    #pragma unroll
    for (int i = 0; i < 2; ++i) {
        float send = (lane & 8) ? b[i] : b[i + 2];
        float recv = __shfl_xor(send, 8, 64);
        float keep = (lane & 8) ? b[i + 2] : b[i];
        c[i] = keep + recv;
    }
    float e;
    {
        float send = (lane & 4) ? c[0] : c[1];
        float recv = __shfl_xor(send, 4, 64);
        float keep = (lane & 4) ? c[1] : c[0];
        e = keep + recv;
    }
    e += __shfl_xor(e, 2, 64);
    e += __shfl_xor(e, 1, 64);
    return e;
}

static __device__ __forceinline__ int bfly_d(int lane) {
    return ((lane & 4) ? 1 : 0) | ((lane & 8) ? 2 : 0)
         | ((lane & 16) ? 4 : 0) | ((lane & 32) ? 8 : 0);
}

// ---- fused input packing: blocks [0,720) pack W, [720,1872) pack x ----
__global__ __launch_bounds__(256)
void k_pack(const float4* __restrict__ W4, u4* __restrict__ Wt,
            const float4* __restrict__ x4, u4* __restrict__ xp) {
    int bid = blockIdx.x;
    if (bid < 720) {                      // 720*256 == NCLS*NCAPS*KDO exactly
        int tid = bid * 256 + threadIdx.x;          // (c*NCAPS+i)*KDO + d
        int d = tid & 15;
        int rest = tid >> 4;
        int i = rest % NCAPS;
        int c = rest / NCAPS;
        float4 a = W4[2 * tid];
        float4 b = W4[2 * tid + 1];
        u4 o;
        o.x = pack2h(a.x, a.y);
        o.y = pack2h(a.z, a.w);
        o.z = pack2h(b.x, b.y);
        o.w = pack2h(b.z, b.w);
        Wt[(size_t)(c * KDO + d) * NCAPS + i] = o;
    } else {                              // 1152*256 == NB*NCAPS exactly
        int tid = (bid - 720) * 256 + threadIdx.x;  // b*NCAPS + i
        float4 a = x4[2 * tid];
        float4 b = x4[2 * tid + 1];
        u4 o;
        o.x = pack2h(a.x, a.y);
        o.y = pack2h(a.z, a.w);
        o.z = pack2h(b.x, b.y);
        o.w = pack2h(b.z, b.w);
        xp[tid] = o;
    }
}

// ---- phase 1: ut + uniform-weight partial sums (s0).
// grid (NCH, NB/8, 10): 1 class x 8 batches per block, 128 threads = 2 waves.
__global__ __launch_bounds__(CHUNK, 1)
void k_uhat(const u4* __restrict__ Wt, const u4* __restrict__ xp,
            u4* __restrict__ ut, float* __restrict__ psum)
{
    __shared__ float red0[2][BBAT][KDO];           // [wave][k][d], 1 KB
    const int t    = threadIdx.x;
    const int lane = t & 63;
    const int wave = t >> 6;
    const int ii = blockIdx.x * CHUNK + t;
    const int b0 = blockIdx.y * BBAT;
    const int c  = blockIdx.z;
    const int dm = bfly_d(lane);

    u4 xq[BBAT];
    #pragma unroll
    for (int k = 0; k < BBAT; ++k)
        xq[k] = xp[(size_t)(b0 + k) * NCAPS + ii];

    const u4* base = Wt + (size_t)c * KDO * NCAPS + ii;
    u4 r[KDO];                                     // 16 loads in flight
    #pragma unroll
    for (int d = 0; d < KDO; ++d)
        r[d] = base[(size_t)d * NCAPS];            // regular load: W stays L2

    #pragma unroll
    for (int k = 0; k < BBAT; ++k) {               // reuse W for 8 batches
        const unsigned* xh = (const unsigned*)&xq[k];
        u4 h0, h1;
        float sacc[KDO];                           // f32 u before f16 rounding
        #pragma unroll
        for (int dp = 0; dp < 8; ++dp) {
            float u0 = dot8h(r[2 * dp],     xh);
            float u1 = dot8h(r[2 * dp + 1], xh);
            sacc[2 * dp]     = u0;
            sacc[2 * dp + 1] = u1;
            unsigned pk = pack2h(u0, u1);
            if (dp < 4) ((unsigned*)&h0)[dp] = pk;
            else        ((unsigned*)&h1)[dp - 4] = pk;
        }
        u4* utb = ut + (size_t)(b0 + k) * NCLS * 2 * NCAPS;
        utb[((size_t)c * 2 + 0) * NCAPS + ii] = h0;
        utb[((size_t)c * 2 + 1) * NCAPS + ii] = h1;

        float e = bfly16(sacc, lane);
        if ((lane & 3) == 0) red0[wave][k][dm] = e;
    }
    __syncthreads();
    {   // 8k x 16d = 128 entries, exactly one per thread
        int k = t >> 4, d = t & 15;
        float v = red0[0][k][d] + red0[1][k][d];
        psum[(((size_t)(b0 + k) * NCH + blockIdx.x) * NCLS + c) * KDO + d] = v;
    }
}

// ---- phase 2 (fused, x2): in-block v from psum + agreement + softmax +
// weighted partial-sum. grid (NCH, NB), 128 threads; reads ut ONCE.
// v_logit = squash(scaleA*sum(psA)) [+ squash(sum(psB)) if psB].
// psum traffic is float4-vectorized: wave0 sums psA, wave1 sums psB.
__global__ __launch_bounds__(CHUNK, 1)
void k_iter(const u4* __restrict__ ut,
            const float* __restrict__ psA, float scaleA,
            const float* __restrict__ psB,
            float* __restrict__ psOut)
{
    __shared__ __align__(16) float s0sh[NCLS * KDO];
    __shared__ __align__(16) float s1sh[NCLS * KDO];
    __shared__ float scsh[2][NCLS];
    __shared__ unsigned vsh[NCLS * 8];
    __shared__ float red[2][NCLS * KDO];               // per-wave partials
    const int t    = threadIdx.x;
    const int lane = t & 63;
    const int wave = t >> 6;
    const int ii = blockIdx.x * CHUNK + t;
    const int b  = blockIdx.y;
    const int dm = bfly_d(lane);

    // ---- in-block squash: s = sum of 9 chunk partials (float4) ----
    if (t < 40) {                                      // wave0: psA
        const float4* pA4 = (const float4*)psA + (size_t)b * NCH * 40;
        float4 s = {0.f, 0.f, 0.f, 0.f};
        #pragma unroll
        for (int ch = 0; ch < NCH; ++ch) {
            float4 v = pA4[ch * 40 + t];
            s.x += v.x; s.y += v.y; s.z += v.z; s.w += v.w;
        }
        float4 o = {s.x * scaleA, s.y * scaleA, s.z * scaleA, s.w * scaleA};
        ((float4*)s0sh)[t] = o;
    } else if (psB && t >= 64 && t < 104) {            // wave1: psB
        const int j = t - 64;
        const float4* pB4 = (const float4*)psB + (size_t)b * NCH * 40;
        float4 s = {0.f, 0.f, 0.f, 0.f};
        #pragma unroll
        for (int ch = 0; ch < NCH; ++ch) {
            float4 v = pB4[ch * 40 + j];
            s.x += v.x; s.y += v.y; s.z += v.z; s.w += v.w;
        }
        ((float4*)s1sh)[j] = s;
    }
    __syncthreads();
    if (t < (psB ? 2 * NCLS : NCLS)) {
        int which = t >= NCLS;
        int c = which ? t - NCLS : t;
        const float* ss = which ? s1sh : s0sh;
        float nsq = 0.f;
        #pragma unroll
        for (int d = 0; d < KDO; ++d) {
            float x = ss[c * KDO + d];
            nsq += x * x;
        }
        scsh[which][c] = sqrtf(nsq) / (1.f + nsq);
    }
    __syncthreads();
    if (t < NCLS * 8) {
        int c = t >> 3, dp = t & 7;
        float va = s0sh[c * KDO + 2 * dp]     * scsh[0][c];
        float vb = s0sh[c * KDO + 2 * dp + 1] * scsh[0][c];
        if (psB) {
            va += s1sh[c * KDO + 2 * dp]     * scsh[1][c];
            vb += s1sh[c * KDO + 2 * dp + 1] * scsh[1][c];
        }
        vsh[t] = pack2h(va, vb);
    }
    __syncthreads();

    // ---- agreement + softmax + weighted sum ----
    const u4* utb = ut + (size_t)b * NCLS * 2 * NCAPS;

    u4 up0[NCLS], up1[NCLS];
    #pragma unroll
    for (int c = 0; c < NCLS; ++c) {
        up0[c] = utb[((size_t)c * 2 + 0) * NCAPS + ii];
        up1[c] = utb[((size_t)c * 2 + 1) * NCAPS + ii];
    }

    float bl[NCLS];
    #pragma unroll
    for (int c = 0; c < NCLS; ++c) {
        float a = 0.f;
        #pragma unroll
        for (int dp = 0; dp < 4; ++dp)
            a = dot2h(((const unsigned*)&up0[c])[dp], vsh[c * 8 + dp], a);
        #pragma unroll
        for (int dp = 0; dp < 4; ++dp)
            a = dot2h(((const unsigned*)&up1[c])[dp], vsh[c * 8 + 4 + dp], a);
        bl[c] = a;
    }

    float m = bl[0];
    #pragma unroll
    for (int c = 1; c < NCLS; ++c) m = fmaxf(m, bl[c]);
    float den = 0.f;
    #pragma unroll
    for (int c = 0; c < NCLS; ++c) den += __expf(bl[c] - m);
    float sid = 1.f / den;
    #pragma unroll
    for (int c = 0; c < NCLS; ++c) bl[c] = __expf(bl[c] - m) * sid;  // bl := w

    #pragma unroll
    for (int c = 0; c < NCLS; ++c) {
        float sacc[KDO];
        #pragma unroll
        for (int dp = 0; dp < 8; ++dp) {
            union { unsigned u; h2_t h; } p;
            p.u = (dp < 4) ? ((const unsigned*)&up0[c])[dp]
                           : ((const unsigned*)&up1[c])[dp - 4];
            sacc[2 * dp]     = bl[c] * (float)p.h.x;
            sacc[2 * dp + 1] = bl[c] * (float)p.h.y;
        }
        float e = bfly16(sacc, lane);
        if ((lane & 3) == 0) red[wave][c * KDO + dm] = e;
    }
    __syncthreads();
    if (t < 40) {                                      // float4 psOut write
        float4 o;
        o.x = red[0][4 * t + 0] + red[1][4 * t + 0];
        o.y = red[0][4 * t + 1] + red[1][4 * t + 1];
        o.z = red[0][4 * t + 2] + red[1][4 * t + 2];
        o.w = red[0][4 * t + 3] + red[1][4 * t + 3];
        ((float4*)(psOut + ((size_t)b * NCH + blockIdx.x) * (NCLS * KDO)))[t] = o;
    }
}

// ---- phase 3 (final only): sum 9 chunk-partials (float4), squash, out.
__global__ __launch_bounds__(160)
void k_squash(const float* __restrict__ psum, float* __restrict__ out)
{
    __shared__ __align__(16) float ssh[NCLS * KDO];
    const int b = blockIdx.x;
    const int t = threadIdx.x;                         // 0..159

    if (t < 40) {
        const float4* p4 = (const float4*)psum + (size_t)b * NCH * 40;
        float4 s = {0.f, 0.f, 0.f, 0.f};
        #pragma unroll
        for (int ch = 0; ch < NCH; ++ch) {
            float4 v = p4[ch * 40 + t];
            s.x += v.x; s.y += v.y; s.z += v.z; s.w += v.w;
        }
        ((float4*)ssh)[t] = s;
    }
    __syncthreads();
    if (t >= NCLS * KDO) return;

    float s = ssh[t];
    float nsq = s * s;                                 // reduce within c-group
    nsq += __shfl_xor(nsq, 8, 16);
    nsq += __shfl_xor(nsq, 4, 16);
    nsq += __shfl_xor(nsq, 2, 16);
    nsq += __shfl_xor(nsq, 1, 16);
    float sc = sqrtf(nsq) / (1.f + nsq);               // (nsq/(1+nsq))/sqrt(nsq)
    out[(size_t)b * NCLS * KDO + t] = s * sc;
}

// ---- fallback (small ws): round-1 fp32 fused kernel, proven correct ----
__global__ __launch_bounds__(256, 2)
void caps_routing_fb(const float* __restrict__ x, const float* __restrict__ W,
                     float* __restrict__ out)
{
    const int b    = blockIdx.x;
    const int t    = threadIdx.x;
    const int lane = t & 63;
    const int wave = t >> 6;
    __shared__ float v_prev[NCLS * KDO];
    __shared__ float redf[NCLS * 4 * KDO];
    float4 xr[5][2];
    const float4* x4 = reinterpret_cast<const float4*>(x + (size_t)b * NCAPS * 8);
    #pragma unroll
    for (int j = 0; j < 5; ++j) {
        int i = t + 256 * j;
        if (i < NCAPS) { xr[j][0] = x4[2 * i]; xr[j][1] = x4[2 * i + 1]; }
    }
    float blog[5][NCLS];
    #pragma unroll
    for (int j = 0; j < 5; ++j)
        #pragma unroll
        for (int c = 0; c < NCLS; ++c) blog[j][c] = 0.f;
    const float4* W4 = reinterpret_cast<const float4*>(W);
    for (int it = 0; it < 3; ++it) {
        if (it > 0) {
            for (int c = 0; c < NCLS; ++c) {
                float vp[KDO];
                #pragma unroll
                for (int d = 0; d < KDO; ++d) vp[d] = v_prev[c * KDO + d];
                #pragma unroll
                for (int j = 0; j < 5; ++j) {
                    int i = t + 256 * j;
                    if (i < NCAPS) {
                        size_t wbx = (size_t)(c * NCAPS + i) * 32;
                        float a = 0.f;
                        #pragma unroll
                        for (int d = 0; d < KDO; ++d) {
                            float4 w0 = W4[wbx + 2 * d]; float4 w1 = W4[wbx + 2 * d + 1];
                            float u = w0.x*xr[j][0].x + w0.y*xr[j][0].y + w0.z*xr[j][0].z
                                    + w0.w*xr[j][0].w + w1.x*xr[j][1].x + w1.y*xr[j][1].y
                                    + w1.z*xr[j][1].z + w1.w*xr[j][1].w;
                            a += u * vp[d];
                        }
                        blog[j][c] += a;
                    }
                }
            }
        }
        float sm2[5], sid2[5];
        #pragma unroll
        for (int j = 0; j < 5; ++j) {
            int i = t + 256 * j;
            if (i < NCAPS) {
                float m = blog[j][0];
                #pragma unroll
                for (int c = 1; c < NCLS; ++c) m = fmaxf(m, blog[j][c]);
                float den = 0.f;
                #pragma unroll
                for (int c = 0; c < NCLS; ++c) den += __expf(blog[j][c] - m);
                sm2[j] = m; sid2[j] = 1.f / den;
            }
        }
        for (int c = 0; c < NCLS; ++c) {
            float acc[KDO];
            #pragma unroll
            for (int d = 0; d < KDO; ++d) acc[d] = 0.f;
            #pragma unroll
            for (int j = 0; j < 5; ++j) {
                int i = t + 256 * j;
                if (i < NCAPS) {
                    float wq = __expf(blog[j][c] - sm2[j]) * sid2[j];
                    size_t wbx = (size_t)(c * NCAPS + i) * 32;
                    #pragma unroll
                    for (int d = 0; d < KDO; ++d) {
                        float4 w0 = W4[wbx + 2 * d]; float4 w1 = W4[wbx + 2 * d + 1];
                        float u = w0.x*xr[j][0].x + w0.y*xr[j][0].y + w0.z*xr[j][0].z
                                + w0.w*xr[j][0].w + w1.x*xr[j][1].x + w1.y*xr[j][1].y
                                + w1.z*xr[j][1].z + w1.w*xr[j][1].w;
                        acc[d] += wq * u;
                    }
                }
            }
            #pragma unroll
            for (int d = 0; d < KDO; ++d) {
                float v = acc[d];
                v += __shfl_xor(v, 32, 64); v += __shfl_xor(v, 16, 64);
                v += __shfl_xor(v,  8, 64); v += __shfl_xor(v,  4, 64);
                v += __shfl_xor(v,  2, 64); v += __shfl_xor(v,  1, 64);
                if (lane == 0) redf[(c * 4 + wave) * KDO + d] = v;
            }
        }
        __syncthreads();
        if (t < NCLS * KDO) {
            int c = t >> 4, d = t & 15;
            float s = redf[(c*4+0)*KDO+d] + redf[(c*4+1)*KDO+d]
                    + redf[(c*4+2)*KDO+d] + redf[(c*4+3)*KDO+d];
            float nsq = s * s;
            nsq += __shfl_xor(nsq, 8, 16); nsq += __shfl_xor(nsq, 4, 16);
            nsq += __shfl_xor(nsq, 2, 16); nsq += __shfl_xor(nsq, 1, 16);
            float scale = sqrtf(nsq) / (1.f + nsq);
            float vv = s * scale;
            v_prev[t] = vv;
            if (it == 2) out[(size_t)b * NCLS * KDO + t] = vv;
        }
        __syncthreads();
    }
}

extern "C" void kernel_launch(void* const* d_in, const int* in_sizes, int n_in,
                              void* d_out, int out_size, void* d_ws, size_t ws_size,
                              hipStream_t stream) {
    const float* x = (const float*)d_in[0];              // [256, 1152, 8] fp32
    const float4* W4 = (const float4*)d_in[1];           // [10, 1152, 1, 16, 8] fp32
    float* out = (float*)d_out;                          // [256, 10, 1, 16] fp32
    (void)in_sizes; (void)n_in; (void)out_size;

    const size_t WT = (size_t)NCLS * KDO * NCAPS * sizeof(u4);            //  2.95 MB
    const size_t XH = (size_t)NB * NCAPS * sizeof(u4);                    //  4.72 MB
    const size_t UT = (size_t)NB * NCLS * 2 * NCAPS * sizeof(u4);         // 94.37 MB
    const size_t PS = (size_t)NB * NCH * NCLS * KDO * sizeof(float);      //  1.47 MB
    const size_t need = WT + XH + UT + 3 * PS;                            // ~106 MB

    if (ws_size >= need) {
        char* p = (char*)d_ws;
        u4* Wt    = (u4*)p;    p += WT;
        u4* xp    = (u4*)p;    p += XH;
        u4* ut    = (u4*)p;    p += UT;
        float* ps0 = (float*)p; p += PS;
        float* ps1 = (float*)p; p += PS;
        float* ps2 = (float*)p;

        k_pack<<<dim3(720 + 1152), dim3(256), 0, stream>>>(
            W4, Wt, (const float4*)x, xp);
        k_uhat<<<dim3(NCH, NB / BBAT, NCLS), dim3(CHUNK), 0, stream>>>(
            Wt, xp, ut, ps0);
        k_iter<<<dim3(NCH, NB), dim3(CHUNK), 0, stream>>>(ut, ps0, 0.1f, nullptr, ps1);
        k_iter<<<dim3(NCH, NB), dim3(CHUNK), 0, stream>>>(ut, ps0, 0.1f, ps1, ps2);
        k_squash<<<dim3(NB), dim3(160), 0, stream>>>(ps2, out);
    } else {
        caps_routing_fb<<<dim3(NB), dim3(256), 0, stream>>>(x, (const float*)d_in[1], out);
    }
}

// Round 11
// 129.876 us; speedup vs baseline: 2.5273x; 1.0276x over previous
//
#include <hip/hip_runtime.h>

// DigitCapsules dynamic routing. Round-28 = class-split k_iter (2x waves).
//  - R27: 133.5 us (psum float4 ~= neutral, like R25's occupancy tweak).
//    All small edits exhausted; big passes run at 2-3 TB/s vs 6.2 for fills.
//    k_iter cause: 1 thread/(capsule,batch) = 4.5 waves/SIMD, one-shot
//    [20 ld -> wait -> ~900 VALU -> 170 DS] per wave => mem pipe idles.
//  - FIX: 2 threads per capsule (5 classes each). 256-thr blocks, 4 waves:
//    wave = (class-half, capsule-subchunk). 8-9 waves/SIMD, half the load
//    chain (10 u4, ~40 VGPR), half the VALU/DS chain. Softmax max/den
//    exchanged with partner t^128 via LDS (2 arrays + 2 syncs). Weighted
//    sum + bfly16 unchanged per wave (64 lanes = 64 capsules, one class).
//  - k_uhat / k_pack / k_squash byte-identical to R27 (isolate the change).
//  - Pipeline (5 launches): k_pack, k_uhat(+s0), k_iter, k_iter, k_squash.
//    Predicted 133 -> ~113-120 us.

#define NCLS   10
#define NCAPS  1152
#define KDO    16
#define CHUNK  128
#define NCH    9           // 1152 / 128
#define NB     256
#define BBAT   8           // batches per k_uhat block

typedef _Float16 h2_t __attribute__((ext_vector_type(2)));
typedef unsigned u4 __attribute__((ext_vector_type(4)));

static __device__ __forceinline__ unsigned pack2h(float a, float b) {
    union { _Float16 h[2]; unsigned u; } p;
    p.h[0] = (_Float16)a;
    p.h[1] = (_Float16)b;
    return p.u;
}

static __device__ __forceinline__ float dot8h(u4 r, const unsigned* xh) {
    union { unsigned u; h2_t h; } w0, w1, w2, w3, a0, a1, a2, a3;
    w0.u = r.x; w1.u = r.y; w2.u = r.z; w3.u = r.w;
    a0.u = xh[0]; a1.u = xh[1]; a2.u = xh[2]; a3.u = xh[3];
#if __has_builtin(__builtin_amdgcn_fdot2)
    float acc = __builtin_amdgcn_fdot2(w0.h, a0.h, 0.f, false);
    acc = __builtin_amdgcn_fdot2(w1.h, a1.h, acc, false);
    acc = __builtin_amdgcn_fdot2(w2.h, a2.h, acc, false);
    acc = __builtin_amdgcn_fdot2(w3.h, a3.h, acc, false);
    return acc;
#else
    return (float)w0.h.x * (float)a0.h.x + (float)w0.h.y * (float)a0.h.y
         + (float)w1.h.x * (float)a1.h.x + (float)w1.h.y * (float)a1.h.y
         + (float)w2.h.x * (float)a2.h.x + (float)w2.h.y * (float)a2.h.y
         + (float)w3.h.x * (float)a3.h.x + (float)w3.h.y * (float)a3.h.y;
#endif
}

static __device__ __forceinline__ float dot2h(unsigned a, unsigned b, float acc) {
    union { unsigned u; h2_t h; } pa, pb;
    pa.u = a; pb.u = b;
#if __has_builtin(__builtin_amdgcn_fdot2)
    return __builtin_amdgcn_fdot2(pa.h, pb.h, acc, false);
#else
    return acc + (float)pa.h.x * (float)pb.h.x + (float)pa.h.y * (float)pb.h.y;
#endif
}

// Butterfly reduce of 16 per-lane values across a 64-lane wave: 17 shuffles.
// Lane l ends with S[d(l)], d = (l&4?1:0)|(l&8?2:0)|(l&16?4:0)|(l&32?8:0).
static __device__ __forceinline__ float bfly16(const float v[KDO], int lane) {
    float a[8];
    #pragma unroll
    for (int i = 0; i < 8; ++i) {
        float send = (lane & 32) ? v[i] : v[i + 8];
        float recv = __shfl_xor(send, 32, 64);
        float keep = (lane & 32) ? v[i + 8] : v[i];
        a[i] = keep + recv;
    }
    float b[4];
    #pragma unroll
    for (int i = 0; i < 4; ++i) {
        float send = (lane & 16) ? a[i] : a[i + 4];
        float recv = __shfl_xor(send, 16, 64);
        float keep = (lane & 16) ? a[i + 4] : a[i];
        b[i] = keep + recv;
    }
    float c[2];
    #pragma unroll
    for (int i = 0; i < 2; ++i) {
        float send = (lane & 8) ? b[i] : b[i + 2];
        float recv = __shfl_xor(send, 8, 64);
        float keep = (lane & 8) ? b[i + 2] : b[i];
        c[i] = keep + recv;
    }
    float e;
    {
        float send = (lane & 4) ? c[0] : c[1];
        float recv = __shfl_xor(send, 4, 64);
        float keep = (lane & 4) ? c[1] : c[0];
        e = keep + recv;
    }
    e += __shfl_xor(e, 2, 64);
    e += __shfl_xor(e, 1, 64);
    return e;
}

static __device__ __forceinline__ int bfly_d(int lane) {
    return ((lane & 4) ? 1 : 0) | ((lane & 8) ? 2 : 0)
         | ((lane & 16) ? 4 : 0) | ((lane & 32) ? 8 : 0);
}

// ---- fused input packing: blocks [0,720) pack W, [720,1872) pack x ----
__global__ __launch_bounds__(256)
void k_pack(const float4* __restrict__ W4, u4* __restrict__ Wt,
            const float4* __restrict__ x4, u4* __restrict__ xp) {
    int bid = blockIdx.x;
    if (bid < 720) {                      // 720*256 == NCLS*NCAPS*KDO exactly
        int tid = bid * 256 + threadIdx.x;          // (c*NCAPS+i)*KDO + d
        int d = tid & 15;
        int rest = tid >> 4;
        int i = rest % NCAPS;
        int c = rest / NCAPS;
        float4 a = W4[2 * tid];
        float4 b = W4[2 * tid + 1];
        u4 o;
        o.x = pack2h(a.x, a.y);
        o.y = pack2h(a.z, a.w);
        o.z = pack2h(b.x, b.y);
        o.w = pack2h(b.z, b.w);
        Wt[(size_t)(c * KDO + d) * NCAPS + i] = o;
    } else {                              // 1152*256 == NB*NCAPS exactly
        int tid = (bid - 720) * 256 + threadIdx.x;  // b*NCAPS + i
        float4 a = x4[2 * tid];
        float4 b = x4[2 * tid + 1];
        u4 o;
        o.x = pack2h(a.x, a.y);
        o.y = pack2h(a.z, a.w);
        o.z = pack2h(b.x, b.y);
        o.w = pack2h(b.z, b.w);
        xp[tid] = o;
    }
}

// ---- phase 1: ut + uniform-weight partial sums (s0).
// grid (NCH, NB/8, 10): 1 class x 8 batches per block, 128 threads = 2 waves.
__global__ __launch_bounds__(CHUNK, 1)
void k_uhat(const u4* __restrict__ Wt, const u4* __restrict__ xp,
            u4* __restrict__ ut, float* __restrict__ psum)
{
    __shared__ float red0[2][BBAT][KDO];           // [wave][k][d], 1 KB
    const int t    = threadIdx.x;
    const int lane = t & 63;
    const int wave = t >> 6;
    const int ii = blockIdx.x * CHUNK + t;
    const int b0 = blockIdx.y * BBAT;
    const int c  = blockIdx.z;
    const int dm = bfly_d(lane);

    u4 xq[BBAT];
    #pragma unroll
    for (int k = 0; k < BBAT; ++k)
        xq[k] = xp[(size_t)(b0 + k) * NCAPS + ii];

    const u4* base = Wt + (size_t)c * KDO * NCAPS + ii;
    u4 r[KDO];                                     // 16 loads in flight
    #pragma unroll
    for (int d = 0; d < KDO; ++d)
        r[d] = base[(size_t)d * NCAPS];            // regular load: W stays L2

    #pragma unroll
    for (int k = 0; k < BBAT; ++k) {               // reuse W for 8 batches
        const unsigned* xh = (const unsigned*)&xq[k];
        u4 h0, h1;
        float sacc[KDO];                           // f32 u before f16 rounding
        #pragma unroll
        for (int dp = 0; dp < 8; ++dp) {
            float u0 = dot8h(r[2 * dp],     xh);
            float u1 = dot8h(r[2 * dp + 1], xh);
            sacc[2 * dp]     = u0;
            sacc[2 * dp + 1] = u1;
            unsigned pk = pack2h(u0, u1);
            if (dp < 4) ((unsigned*)&h0)[dp] = pk;
            else        ((unsigned*)&h1)[dp - 4] = pk;
        }
        u4* utb = ut + (size_t)(b0 + k) * NCLS * 2 * NCAPS;
        utb[((size_t)c * 2 + 0) * NCAPS + ii] = h0;
        utb[((size_t)c * 2 + 1) * NCAPS + ii] = h1;

        float e = bfly16(sacc, lane);
        if ((lane & 3) == 0) red0[wave][k][dm] = e;
    }
    __syncthreads();
    {   // 8k x 16d = 128 entries, exactly one per thread
        int k = t >> 4, d = t & 15;
        float v = red0[0][k][d] + red0[1][k][d];
        psum[(((size_t)(b0 + k) * NCH + blockIdx.x) * NCLS + c) * KDO + d] = v;
    }
}

// ---- phase 2 (fused, x2): in-block v from psum + agreement + softmax +
// weighted partial-sum. grid (NCH, NB), 256 threads = 4 waves:
// wave = (class-half<<1) | capsule-subchunk; each thread owns 1 capsule x
// 5 classes (10 u4). Softmax max/den exchanged with partner t^128 via LDS.
__global__ __launch_bounds__(256)
void k_iter(const u4* __restrict__ ut,
            const float* __restrict__ psA, float scaleA,
            const float* __restrict__ psB,
            float* __restrict__ psOut)
{
    __shared__ __align__(16) float s0sh[NCLS * KDO];
    __shared__ __align__(16) float s1sh[NCLS * KDO];
    __shared__ float scsh[2][NCLS];
    __shared__ unsigned vsh[NCLS * 8];
    __shared__ float red[4][5 * KDO];                  // [wave][5c x 16d]
    __shared__ float msh[256];                         // softmax max exchange
    __shared__ float dsh[256];                         // softmax den exchange
    const int t    = threadIdx.x;
    const int lane = t & 63;
    const int wave = t >> 6;                           // 0..3
    const int sub  = wave & 1;                         // capsule subchunk
    const int half = wave >> 1;                        // class half (0/1)
    const int c0   = half * 5;
    const int ii   = blockIdx.x * CHUNK + sub * 64 + lane;
    const int b    = blockIdx.y;
    const int dm   = bfly_d(lane);

    // ---- in-block squash: s = sum of 9 chunk partials (float4) ----
    if (t < 40) {                                      // wave0: psA
        const float4* pA4 = (const float4*)psA + (size_t)b * NCH * 40;
        float4 s = {0.f, 0.f, 0.f, 0.f};
        #pragma unroll
        for (int ch = 0; ch < NCH; ++ch) {
            float4 v = pA4[ch * 40 + t];
            s.x += v.x; s.y += v.y; s.z += v.z; s.w += v.w;
        }
        float4 o = {s.x * scaleA, s.y * scaleA, s.z * scaleA, s.w * scaleA};
        ((float4*)s0sh)[t] = o;
    } else if (psB && t >= 64 && t < 104) {            // wave1: psB
        const int j = t - 64;
        const float4* pB4 = (const float4*)psB + (size_t)b * NCH * 40;
        float4 s = {0.f, 0.f, 0.f, 0.f};
        #pragma unroll
        for (int ch = 0; ch < NCH; ++ch) {
            float4 v = pB4[ch * 40 + j];
            s.x += v.x; s.y += v.y; s.z += v.z; s.w += v.w;
        }
        ((float4*)s1sh)[j] = s;
    }
    __syncthreads();
    if (t < (psB ? 2 * NCLS : NCLS)) {
        int which = t >= NCLS;
        int c = which ? t - NCLS : t;
        const float* ss = which ? s1sh : s0sh;
        float nsq = 0.f;
        #pragma unroll
        for (int d = 0; d < KDO; ++d) {
            float x = ss[c * KDO + d];
            nsq += x * x;
        }
        scsh[which][c] = sqrtf(nsq) / (1.f + nsq);
    }
    __syncthreads();
    if (t < NCLS * 8) {
        int c = t >> 3, dp = t & 7;
        float va = s0sh[c * KDO + 2 * dp]     * scsh[0][c];
        float vb = s0sh[c * KDO + 2 * dp + 1] * scsh[0][c];
        if (psB) {
            va += s1sh[c * KDO + 2 * dp]     * scsh[1][c];
            vb += s1sh[c * KDO + 2 * dp + 1] * scsh[1][c];
        }
        vsh[t] = pack2h(va, vb);
    }
    __syncthreads();

    // ---- load u for this thread's capsule, its 5 classes ----
    const u4* utb = ut + (size_t)b * NCLS * 2 * NCAPS;
    u4 up0[5], up1[5];
    #pragma unroll
    for (int j = 0; j < 5; ++j) {
        int c = c0 + j;
        up0[j] = utb[((size_t)c * 2 + 0) * NCAPS + ii];
        up1[j] = utb[((size_t)c * 2 + 1) * NCAPS + ii];
    }

    // ---- logits for 5 classes ----
    float bl[5];
    #pragma unroll
    for (int j = 0; j < 5; ++j) {
        int c = c0 + j;
        float a = 0.f;
        #pragma unroll
        for (int dp = 0; dp < 4; ++dp)
            a = dot2h(((const unsigned*)&up0[j])[dp], vsh[c * 8 + dp], a);
        #pragma unroll
        for (int dp = 0; dp < 4; ++dp)
            a = dot2h(((const unsigned*)&up1[j])[dp], vsh[c * 8 + 4 + dp], a);
        bl[j] = a;
    }

    // ---- softmax across 10 classes: exchange with partner (t^128) ----
    float m5 = bl[0];
    #pragma unroll
    for (int j = 1; j < 5; ++j) m5 = fmaxf(m5, bl[j]);
    msh[t] = m5;
    __syncthreads();
    float m = fmaxf(m5, msh[t ^ 128]);
    float dp5 = 0.f;
    #pragma unroll
    for (int j = 0; j < 5; ++j) dp5 += __expf(bl[j] - m);
    dsh[t] = dp5;
    __syncthreads();
    float sid = 1.f / (dp5 + dsh[t ^ 128]);
    #pragma unroll
    for (int j = 0; j < 5; ++j) bl[j] = __expf(bl[j] - m) * sid;  // bl := w

    // ---- weighted sum, butterfly reduce per class over this wave ----
    #pragma unroll
    for (int j = 0; j < 5; ++j) {
        float sacc[KDO];
        #pragma unroll
        for (int dp = 0; dp < 8; ++dp) {
            union { unsigned u; h2_t h; } p;
            p.u = (dp < 4) ? ((const unsigned*)&up0[j])[dp]
                           : ((const unsigned*)&up1[j])[dp - 4];
            sacc[2 * dp]     = bl[j] * (float)p.h.x;
            sacc[2 * dp + 1] = bl[j] * (float)p.h.y;
        }
        float e = bfly16(sacc, lane);
        if ((lane & 3) == 0) red[wave][j * KDO + dm] = e;
    }
    __syncthreads();
    if (t < 40) {                                      // float4 psOut write
        // t<20: classes 0-4 in waves 0,1 (idx 4t); t>=20: classes 5-9 in
        // waves 2,3 (idx 4(t-20)).
        int w0 = (t < 20) ? 0 : 2;
        int ix = (t < 20) ? 4 * t : 4 * (t - 20);
        float4 o;
        o.x = red[w0][ix + 0] + red[w0 + 1][ix + 0];
        o.y = red[w0][ix + 1] + red[w0 + 1][ix + 1];
        o.z = red[w0][ix + 2] + red[w0 + 1][ix + 2];
        o.w = red[w0][ix + 3] + red[w0 + 1][ix + 3];
        ((float4*)(psOut + ((size_t)b * NCH + blockIdx.x) * (NCLS * KDO)))[t] = o;
    }
}

// ---- phase 3 (final only): sum 9 chunk-partials (float4), squash, out.
__global__ __launch_bounds__(160)
void k_squash(const float* __restrict__ psum, float* __restrict__ out)
{
    __shared__ __align__(16) float ssh[NCLS * KDO];
    const int b = blockIdx.x;
    const int t = threadIdx.x;                         // 0..159

    if (t < 40) {
        const float4* p4 = (const float4*)psum + (size_t)b * NCH * 40;
        float4 s = {0.f, 0.f, 0.f, 0.f};
        #pragma unroll
        for (int ch = 0; ch < NCH; ++ch) {
            float4 v = p4[ch * 40 + t];
            s.x += v.x; s.y += v.y; s.z += v.z; s.w += v.w;
        }
        ((float4*)ssh)[t] = s;
    }
    __syncthreads();
    if (t >= NCLS * KDO) return;

    float s = ssh[t];
    float nsq = s * s;                                 // reduce within c-group
    nsq += __shfl_xor(nsq, 8, 16);
    nsq += __shfl_xor(nsq, 4, 16);
    nsq += __shfl_xor(nsq, 2, 16);
    nsq += __shfl_xor(nsq, 1, 16);
    float sc = sqrtf(nsq) / (1.f + nsq);               // (nsq/(1+nsq))/sqrt(nsq)
    out[(size_t)b * NCLS * KDO + t] = s * sc;
}

// ---- fallback (small ws): round-1 fp32 fused kernel, proven correct ----
__global__ __launch_bounds__(256, 2)
void caps_routing_fb(const float* __restrict__ x, const float* __restrict__ W,
                     float* __restrict__ out)
{
    const int b    = blockIdx.x;
    const int t    = threadIdx.x;
    const int lane = t & 63;
    const int wave = t >> 6;
    __shared__ float v_prev[NCLS * KDO];
    __shared__ float redf[NCLS * 4 * KDO];
    float4 xr[5][2];
    const float4* x4 = reinterpret_cast<const float4*>(x + (size_t)b * NCAPS * 8);
    #pragma unroll
    for (int j = 0; j < 5; ++j) {
        int i = t + 256 * j;
        if (i < NCAPS) { xr[j][0] = x4[2 * i]; xr[j][1] = x4[2 * i + 1]; }
    }
    float blog[5][NCLS];
    #pragma unroll
    for (int j = 0; j < 5; ++j)
        #pragma unroll
        for (int c = 0; c < NCLS; ++c) blog[j][c] = 0.f;
    const float4* W4 = reinterpret_cast<const float4*>(W);
    for (int it = 0; it < 3; ++it) {
        if (it > 0) {
            for (int c = 0; c < NCLS; ++c) {
                float vp[KDO];
                #pragma unroll
                for (int d = 0; d < KDO; ++d) vp[d] = v_prev[c * KDO + d];
                #pragma unroll
                for (int j = 0; j < 5; ++j) {
                    int i = t + 256 * j;
                    if (i < NCAPS) {
                        size_t wbx = (size_t)(c * NCAPS + i) * 32;
                        float a = 0.f;
                        #pragma unroll
                        for (int d = 0; d < KDO; ++d) {
                            float4 w0 = W4[wbx + 2 * d]; float4 w1 = W4[wbx + 2 * d + 1];
                            float u = w0.x*xr[j][0].x + w0.y*xr[j][0].y + w0.z*xr[j][0].z
                                    + w0.w*xr[j][0].w + w1.x*xr[j][1].x + w1.y*xr[j][1].y
                                    + w1.z*xr[j][1].z + w1.w*xr[j][1].w;
                            a += u * vp[d];
                        }
                        blog[j][c] += a;
                    }
                }
            }
        }
        float sm2[5], sid2[5];
        #pragma unroll
        for (int j = 0; j < 5; ++j) {
            int i = t + 256 * j;
            if (i < NCAPS) {
                float m = blog[j][0];
                #pragma unroll
                for (int c = 1; c < NCLS; ++c) m = fmaxf(m, blog[j][c]);
                float den = 0.f;
                #pragma unroll
                for (int c = 0; c < NCLS; ++c) den += __expf(blog[j][c] - m);
                sm2[j] = m; sid2[j] = 1.f / den;
            }
        }
        for (int c = 0; c < NCLS; ++c) {
            float acc[KDO];
            #pragma unroll
            for (int d = 0; d < KDO; ++d) acc[d] = 0.f;
            #pragma unroll
            for (int j = 0; j < 5; ++j) {
                int i = t + 256 * j;
                if (i < NCAPS) {
                    float wq = __expf(blog[j][c] - sm2[j]) * sid2[j];
                    size_t wbx = (size_t)(c * NCAPS + i) * 32;
                    #pragma unroll
                    for (int d = 0; d < KDO; ++d) {
                        float4 w0 = W4[wbx + 2 * d]; float4 w1 = W4[wbx + 2 * d + 1];
                        float u = w0.x*xr[j][0].x + w0.y*xr[j][0].y + w0.z*xr[j][0].z
                                + w0.w*xr[j][0].w + w1.x*xr[j][1].x + w1.y*xr[j][1].y
                                + w1.z*xr[j][1].z + w1.w*xr[j][1].w;
                        acc[d] += wq * u;
                    }
                }
            }
            #pragma unroll
            for (int d = 0; d < KDO; ++d) {
                float v = acc[d];
                v += __shfl_xor(v, 32, 64); v += __shfl_xor(v, 16, 64);
                v += __shfl_xor(v,  8, 64); v += __shfl_xor(v,  4, 64);
                v += __shfl_xor(v,  2, 64); v += __shfl_xor(v,  1, 64);
                if (lane == 0) redf[(c * 4 + wave) * KDO + d] = v;
            }
        }
        __syncthreads();
        if (t < NCLS * KDO) {
            int c = t >> 4, d = t & 15;
            float s = redf[(c*4+0)*KDO+d] + redf[(c*4+1)*KDO+d]
                    + redf[(c*4+2)*KDO+d] + redf[(c*4+3)*KDO+d];
            float nsq = s * s;
            nsq += __shfl_xor(nsq, 8, 16); nsq += __shfl_xor(nsq, 4, 16);
            nsq += __shfl_xor(nsq, 2, 16); nsq += __shfl_xor(nsq, 1, 16);
            float scale = sqrtf(nsq) / (1.f + nsq);
            float vv = s * scale;
            v_prev[t] = vv;
            if (it == 2) out[(size_t)b * NCLS * KDO + t] = vv;
        }
        __syncthreads();
    }
}

extern "C" void kernel_launch(void* const* d_in, const int* in_sizes, int n_in,
                              void* d_out, int out_size, void* d_ws, size_t ws_size,
                              hipStream_t stream) {
    const float* x = (const float*)d_in[0];              // [256, 1152, 8] fp32
    const float4* W4 = (const float4*)d_in[1];           // [10, 1152, 1, 16, 8] fp32
    float* out = (float*)d_out;                          // [256, 10, 1, 16] fp32
    (void)in_sizes; (void)n_in; (void)out_size;

    const size_t WT = (size_t)NCLS * KDO * NCAPS * sizeof(u4);            //  2.95 MB
    const size_t XH = (size_t)NB * NCAPS * sizeof(u4);                    //  4.72 MB
    const size_t UT = (size_t)NB * NCLS * 2 * NCAPS * sizeof(u4);         // 94.37 MB
    const size_t PS = (size_t)NB * NCH * NCLS * KDO * sizeof(float);      //  1.47 MB
    const size_t need = WT + XH + UT + 3 * PS;                            // ~106 MB

    if (ws_size >= need) {
        char* p = (char*)d_ws;
        u4* Wt    = (u4*)p;    p += WT;
        u4* xp    = (u4*)p;    p += XH;
        u4* ut    = (u4*)p;    p += UT;
        float* ps0 = (float*)p; p += PS;
        float* ps1 = (float*)p; p += PS;
        float* ps2 = (float*)p;

        k_pack<<<dim3(720 + 1152), dim3(256), 0, stream>>>(
            W4, Wt, (const float4*)x, xp);
        k_uhat<<<dim3(NCH, NB / BBAT, NCLS), dim3(CHUNK), 0, stream>>>(
            Wt, xp, ut, ps0);
        k_iter<<<dim3(NCH, NB), dim3(256), 0, stream>>>(ut, ps0, 0.1f, nullptr, ps1);
        k_iter<<<dim3(NCH, NB), dim3(256), 0, stream>>>(ut, ps0, 0.1f, ps1, ps2);
        k_squash<<<dim3(NB), dim3(160), 0, stream>>>(ps2, out);
    } else {
        caps_routing_fb<<<dim3(NB), dim3(256), 0, stream>>>(x, (const float*)d_in[1], out);
    }
}